// Round 9
// baseline (118.044 us; speedup 1.0000x reference)
//
#include <hip/hip_runtime.h>

// Problem constants (fixed by reference: XSIZE=128, B=8, N=262144)
constexpr unsigned XS        = 128;
constexpr unsigned NB        = 8;
constexpr unsigned NPTS      = 262144;           // 2^18 per batch
constexpr unsigned TOTAL_PTS = NB * NPTS;        // 2^21
constexpr unsigned PPB       = 4096;             // points per bin block
constexpr unsigned NSEG      = TOTAL_PTS / PPB;  // 512 bin blocks (64/batch)
constexpr unsigned NBIN      = 256;              // bins/batch: (i<<1)|(j>=64)
constexpr unsigned NBKT      = NB * NBIN;        // 2048 buckets
constexpr unsigned CAP       = 1536;             // recs/bucket; mean ~1032, +16 sigma
constexpr unsigned STGCAP    = PPB + 256;        // LDS staging incl seam dupes (+40 sigma)

// d_ws layout:
//   rec2 : u64 [NBKT*CAP] = 25.2 MiB (bucket-dense records)
//   gcur : u32 [2048]     = 8 KiB    (bucket cursors, memset 0)
//   stage: f32 [256]      = 1 KiB    (memset 0)
constexpr size_t REC2_U64 = (size_t)NBKT * CAP;

// Record = [val:f32 | bin:8 (bits 14-21) | l:7 (bits 7-13) | k:7 (bits 0-6)]
// l = local row in the 65-row strip; l==64 marks a j==64 seam duplicate.

// ---------------------------------------------------------------------------
// Kernel 1: bin points by (b, i, j-half) into dense global bucket regions.
// 512 blocks x 256 thr, 4096 points each. j==64 points are duplicated into
// the h=0 bucket as seam row l=64.
__global__ __launch_bounds__(256) void bin_kernel(
        const int* __restrict__ idx, const float* __restrict__ vals,
        unsigned long long* __restrict__ rec2, unsigned* __restrict__ gcur) {
    __shared__ unsigned long long sbuf[STGCAP];  // 34 KiB (idx chunks alias low 12 KiB)
    __shared__ unsigned hist[NBIN], cur[NBIN], loff[NBIN], gbase[NBIN];
    __shared__ unsigned sntot;
    unsigned tid = threadIdx.x, g = blockIdx.x;
    unsigned b = g >> 6;                         // 64 blocks per batch
    unsigned base = g * PPB;

    hist[tid] = 0u;                              // tid covers all 256 bins

    // 4 rounds: stage 1024 points' idx (768 uint4) into LDS, extract keys,
    // histogram bins (incl seam dupes); vals loaded coalesced.
    unsigned key[16]; float val[16];
    const unsigned* ibuf = (const unsigned*)sbuf;
    for (unsigned r = 0; r < 4u; ++r) {
        __syncthreads();                         // prev round's reads done
        {
            const uint4* src = (const uint4*)idx + ((size_t)g * 3072u + r * 768u);
            uint4* dst = (uint4*)sbuf;
#pragma unroll
            for (unsigned n = 0; n < 3u; ++n) dst[n * 256u + tid] = src[n * 256u + tid];
        }
        __syncthreads();
#pragma unroll
        for (unsigned n = 0; n < 4u; ++n) {
            unsigned p = n * 256u + tid;
            unsigned i = ibuf[3u * p], j = ibuf[3u * p + 1u], k = ibuf[3u * p + 2u];
            unsigned m = r * 4u + n;
            key[m] = (i << 14) | (j << 7) | k;
            val[m] = vals[base + r * 1024u + p];
            atomicAdd(&hist[(i << 1) | (j >> 6)], 1u);
            if (j == 64u) atomicAdd(&hist[i << 1], 1u);   // seam dupe
        }
    }
    __syncthreads();

    // Exclusive scan of hist[256] by wave 0 (4 chunks with carry).
    if (tid < 64u) {
        unsigned carry = 0u;
#pragma unroll
        for (unsigned c = 0; c < 4u; ++c) {
            unsigned hh = hist[c * 64u + tid];
            unsigned a = hh;
#pragma unroll
            for (unsigned o = 1; o <= 32; o <<= 1) {
                unsigned t = __shfl_up(a, o, 64);
                if (tid >= o) a += t;
            }
            unsigned e = a - hh + carry;
            loff[c * 64u + tid] = e;
            cur[c * 64u + tid]  = e;
            carry += __shfl(a, 63, 64);          // chunk total, broadcast
        }
        if (tid == 0u) sntot = carry;            // total records incl dupes
    }
    __syncthreads();

    // Reserve dense global space per bin.
    gbase[tid] = atomicAdd(&gcur[b * NBIN + tid], hist[tid]);

    // Scatter records into LDS at sorted positions (idx region now dead).
#pragma unroll
    for (unsigned m = 0; m < 16u; ++m) {
        unsigned kk = key[m];
        unsigned i = kk >> 14, j = (kk >> 7) & 127u, k = kk & 127u;
        unsigned be = (i << 1) | (j >> 6);
        unsigned long long vb = (unsigned long long)__float_as_uint(val[m]) << 32;
        unsigned pos = atomicAdd(&cur[be], 1u);
        if (pos < STGCAP)
            sbuf[pos] = vb | (be << 14) | ((j & 63u) << 7) | k;
        if (j == 64u) {                          // seam dupe -> h=0 bucket, row 64
            unsigned be2 = i << 1;
            unsigned pos2 = atomicAdd(&cur[be2], 1u);
            if (pos2 < STGCAP)
                sbuf[pos2] = vb | (be2 << 14) | (64u << 7) | k;
        }
    }
    __syncthreads();

    // Write-out: dense runs (~16 recs = 128 B) into bucket regions.
    unsigned ntot = sntot;
    for (unsigned s = tid; s < ntot; s += 256u) {
        unsigned long long rr = sbuf[s];
        unsigned be = ((unsigned)rr >> 14) & 0xFFu;
        unsigned dst = gbase[be] + (s - loff[be]);
        if (dst < CAP)
            rec2[(size_t)(b * NBIN + be) * CAP + dst] = rr;
    }
}

// ---------------------------------------------------------------------------
// Kernel 2: one block per (b, i, h), 512 thr, 65x128 LDS strip (33 KB,
// ~4 blocks/CU). Every loaded record is used (no j-filter):
//   A: strip = P_i rows [j0..j0+63] (+seam row 64 for h=0)
//   d23 reduce -> B: strip -= P_{i+1} owned rows (skip seam dupes)
//   -> d1 reduce.  |.|,(.)^2 even => no negate needed.
__global__ __launch_bounds__(512) void accum_kernel(
        const unsigned long long* __restrict__ rec2,
        const unsigned* __restrict__ gcur, float* __restrict__ stage) {
    __shared__ float strip[65u * XS];            // 33,280 B
    __shared__ float sred[16];
    unsigned z = blockIdx.x;                     // 0..2047
    unsigned b = z >> 8, rem = z & 255u;         // rem = (i<<1)|h
    unsigned i = rem >> 1, h = rem & 1u;
    unsigned j0 = h << 6;
    bool has_d1 = (i < 127u);
    unsigned tid = threadIdx.x, lane = tid & 63u, w = tid >> 6;

    unsigned cnt0 = min(gcur[b * NBIN + rem], CAP);
    unsigned cnt1 = has_d1 ? min(gcur[b * NBIN + rem + 2u], CAP) : 0u;
    const unsigned long long* bktA = rec2 + (size_t)(b * NBIN + rem) * CAP;
    const unsigned long long* bktB = bktA + 2u * (size_t)CAP;

    // Issue phase-A loads (3 chunks cover CAP); hide under strip zeroing.
    unsigned long long rvA[3]; bool avA[3];
#pragma unroll
    for (unsigned q = 0; q < 3u; ++q) {
        unsigned r = q * 512u + tid;
        avA[q] = r < cnt0;
        if (avA[q]) rvA[q] = bktA[r];
    }

    // Zero the strip (8320 floats = 2080 float4).
    float4* p4 = (float4*)strip;
    for (unsigned r = tid; r < 2080u; r += 512u)
        p4[r] = float4{0.f, 0.f, 0.f, 0.f};
    __syncthreads();

    // Phase A atomics: every record belongs to this strip.
#pragma unroll
    for (unsigned q = 0; q < 3u; ++q)
        if (avA[q])
            atomicAdd(&strip[(unsigned)rvA[q] & 0x3FFFu],
                      __uint_as_float((unsigned)(rvA[q] >> 32)));
    __syncthreads();

    // Issue phase-B loads now; latency hides under the d23 reduce.
    unsigned long long rvB[3]; bool avB[3];
    if (has_d1) {
#pragma unroll
        for (unsigned q = 0; q < 3u; ++q) {
            unsigned r = q * 512u + tid;
            avB[q] = r < cnt1;
            if (avB[q]) rvB[q] = bktB[r];
        }
    }

    // d23 reduce over owned rows: 16 voxels = 4 float4 per thread.
    unsigned jmax = 127u - j0;                   // j-pair valid iff l < jmax
    float tv = 0.f, mse = 0.f;
#pragma unroll
    for (unsigned r = 0; r < 4u; ++r) {
        unsigned v4 = r * 512u + tid;            // float4 idx in [0,2048) = rows [0,64)
        unsigned l = v4 >> 5, k4 = v4 & 31u;
        float4 c = p4[v4];
        float d0 = c.y - c.x, d1 = c.z - c.y, d2 = c.w - c.z;
        tv  += fabsf(d0) + fabsf(d1) + fabsf(d2);
        mse += d0 * d0 + d1 * d1 + d2 * d2;
        if (k4 < 31u) {                          // k-seam within row
            float nx = strip[(v4 << 2) + 4u];
            float d3 = nx - c.w;
            tv += fabsf(d3); mse += d3 * d3;
        }
        if (l < jmax) {                          // j-pair (uses seam row at l=63, h=0)
            float4 n = p4[v4 + 32u];
            float e0 = n.x - c.x, e1 = n.y - c.y, e2 = n.z - c.z, e3 = n.w - c.w;
            tv  += fabsf(e0) + fabsf(e1) + fabsf(e2) + fabsf(e3);
            mse += e0 * e0 + e1 * e1 + e2 * e2 + e3 * e3;
        }
    }

    if (has_d1) {
        __syncthreads();                         // P_i reads done
        // Phase B atomics (sign -1), skipping seam dupes (addr >= 8192).
#pragma unroll
        for (unsigned q = 0; q < 3u; ++q)
            if (avB[q]) {
                unsigned a = (unsigned)rvB[q] & 0x3FFFu;
                if (a < 8192u)
                    atomicAdd(&strip[a],
                              -__uint_as_float((unsigned)(rvB[q] >> 32)));
            }
        __syncthreads();
        // d1 reduce over owned rows.
#pragma unroll
        for (unsigned r = 0; r < 4u; ++r) {
            float4 dd = p4[r * 512u + tid];
            tv  += fabsf(dd.x) + fabsf(dd.y) + fabsf(dd.z) + fabsf(dd.w);
            mse += dd.x * dd.x + dd.y * dd.y + dd.z * dd.z + dd.w * dd.w;
        }
    }

    // Block reduction: wave shuffle, then cross-wave via sred.
#pragma unroll
    for (int o = 32; o > 0; o >>= 1) {
        tv  += __shfl_down(tv, o, 64);
        mse += __shfl_down(mse, o, 64);
    }
    if (lane == 0u) { sred[w] = tv; sred[8u + w] = mse; }
    __syncthreads();
    if (tid == 0u) {
        float tt = 0.f, mm = 0.f;
#pragma unroll
        for (unsigned q = 0; q < 8u; ++q) { tt += sred[q]; mm += sred[8u + q]; }
        atomicAdd(stage + (size_t)b * 16u,        tt);
        atomicAdd(stage + (size_t)(8u + b) * 16u, mm);
    }
}

// ---------------------------------------------------------------------------
// Kernel 3: scale staged sums into d_out (overwrites poison).
__global__ void finalize_kernel(const float* __restrict__ stage,
                                float* __restrict__ out) {
    unsigned i = threadIdx.x;
    if (i < 16u) {
        float s = stage[i * 16u];
        float scale = (i < 8u) ? (1.0f / 2097152.0f)     // / 128^3
                               : (1.0f / 32512.0f);      // / (2*128^2 - 2*128)
        out[i] = s * scale;
    }
}

// ---------------------------------------------------------------------------
extern "C" void kernel_launch(void* const* d_in, const int* in_sizes, int n_in,
                              void* d_out, int out_size, void* d_ws, size_t ws_size,
                              hipStream_t stream) {
    const int*   idx  = (const int*)d_in[0];    // [8, 262144, 3] int32
    const float* vals = (const float*)d_in[1];  // [8, 262144] float32

    unsigned long long* rec2 = (unsigned long long*)d_ws;
    unsigned* gcur  = (unsigned*)(rec2 + REC2_U64);
    float*    stage = (float*)(gcur + NBKT);
    float*    out   = (float*)d_out;

    // Zero cursors (8 KiB) + stage (1 KiB).
    hipMemsetAsync(gcur, 0, NBKT * 4 + 256 * 4, stream);

    bin_kernel<<<NSEG, 256, 0, stream>>>(idx, vals, rec2, gcur);
    accum_kernel<<<NB * NBIN, 512, 0, stream>>>(rec2, gcur, stage);
    finalize_kernel<<<1, 64, 0, stream>>>(stage, out);
}